// Round 4
// baseline (62.581 us; speedup 1.0000x reference)
//
#include <hip/hip_runtime.h>
#include <hip/hip_bf16.h>
#include <hip/hip_cooperative_groups.h>

namespace cg = cooperative_groups;

// loss = N * sum(x*x) - sum_d (colsum_d)^2, x is (256, D=100000) fp32 row-major.
// Single-dispatch cooperative design: 256 blocks (1/CU) x 1024 threads.
// Block b owns float4-columns [D4*b/256, D4*(b+1)/256) (97/98 cols, ~1% imbalance).
// Phase 1: block partial = 256*q_blk - ssq_blk -> ws[b] (agent-scope store).
// grid.sync(); phase 2: block 0 wave 0 sums 256 partials -> d_out (plain store).
// No memset node, no atomics on d_out -> 1-node graph.

#define N_ROWS 256
#define NBLK 256
#define CLANES 128
#define RG 8
#define RPG 32

typedef float f32x4 __attribute__((ext_vector_type(4)));

__device__ __forceinline__ float tpc_block_partial(
    const float* __restrict__ x, int D4, int D) {
  const int c = threadIdx.x & (CLANES - 1);  // 0..127
  const int g = threadIdx.x >> 7;            // 0..7
  const int c0 = (int)(((long)D4 * blockIdx.x) >> 8);
  const int c1 = (int)(((long)D4 * (blockIdx.x + 1)) >> 8);
  const int ncols = c1 - c0;                 // 97 or 98

  f32x4 s = {0.f, 0.f, 0.f, 0.f};
  float q = 0.f;

  if (c < ncols) {
    const float* p = x + (size_t)g * RPG * D + (size_t)(c0 + c) * 4;
#pragma unroll 16
    for (int r = 0; r < RPG; ++r) {
      f32x4 v = *reinterpret_cast<const f32x4*>(p + (size_t)r * D);
      s += v;
      q += v.x * v.x + v.y * v.y + v.z * v.z + v.w * v.w;
    }
  }

#pragma unroll
  for (int off = 32; off > 0; off >>= 1) q += __shfl_down(q, off, 64);

  __shared__ f32x4 sh_s[RG][CLANES];  // 16 KB
  __shared__ float sh_q[16];
  sh_s[g][c] = s;  // inactive cols wrote zeros
  if ((threadIdx.x & 63) == 0) sh_q[threadIdx.x >> 6] = q;
  __syncthreads();

  float result = 0.f;
  if (threadIdx.x < 64) {
    const int l = threadIdx.x;
    float ssq = 0.f;
#pragma unroll
    for (int half = 0; half < 2; ++half) {
      const int cc = l + half * 64;
      f32x4 t = sh_s[0][cc];
#pragma unroll
      for (int i = 1; i < RG; ++i) t += sh_s[i][cc];
      ssq += t.x * t.x + t.y * t.y + t.z * t.z + t.w * t.w;
    }
    float qw = (l < 16) ? sh_q[l] : 0.f;
#pragma unroll
    for (int off = 32; off > 0; off >>= 1) {
      ssq += __shfl_down(ssq, off, 64);
      qw  += __shfl_down(qw, off, 64);
    }
    result = (float)N_ROWS * qw - ssq;  // valid on thread 0
  }
  return result;
}

__global__ __launch_bounds__(1024) void tpc_coop_kernel(
    const float* __restrict__ x, float* __restrict__ ws,
    float* __restrict__ out, int D4, int D) {
  float part = tpc_block_partial(x, D4, D);
  if (threadIdx.x == 0)
    __hip_atomic_store(&ws[blockIdx.x], part, __ATOMIC_RELAXED,
                       __HIP_MEMORY_SCOPE_AGENT);
  cg::this_grid().sync();
  if (blockIdx.x == 0 && threadIdx.x < 64) {
    float v = 0.f;
#pragma unroll
    for (int i = 0; i < 4; ++i)
      v += __hip_atomic_load(&ws[threadIdx.x + 64 * i], __ATOMIC_RELAXED,
                             __HIP_MEMORY_SCOPE_AGENT);
#pragma unroll
    for (int off = 32; off > 0; off >>= 1) v += __shfl_down(v, off, 64);
    if (threadIdx.x == 0) out[0] = v;
  }
}

// Fallback (only if ws is too small): R3 path — memset + per-block atomicAdd.
__global__ __launch_bounds__(1024) void tpc_atomic_kernel(
    const float* __restrict__ x, float* __restrict__ out, int D4, int D) {
  float part = tpc_block_partial(x, D4, D);
  if (threadIdx.x == 0) atomicAdd(out, part);
}

extern "C" void kernel_launch(void* const* d_in, const int* in_sizes, int n_in,
                              void* d_out, int out_size, void* d_ws, size_t ws_size,
                              hipStream_t stream) {
  const float* x = (const float*)d_in[0];
  float* out = (float*)d_out;
  float* ws = (float*)d_ws;
  int total = in_sizes[0];
  int D = total / N_ROWS;   // 100000
  int D4 = D / 4;           // 25000

  if (ws_size >= NBLK * sizeof(float)) {
    void* args[] = {(void*)&x, (void*)&ws, (void*)&out, (void*)&D4, (void*)&D};
    hipLaunchCooperativeKernel((const void*)tpc_coop_kernel, dim3(NBLK),
                               dim3(1024), args, 0, stream);
  } else {
    hipMemsetAsync(d_out, 0, sizeof(float) * out_size, stream);
    tpc_atomic_kernel<<<NBLK, 1024, 0, stream>>>(x, out, D4, D);
  }
}

// Round 5
// 28.980 us; speedup vs baseline: 2.1595x; 2.1595x over previous
//
#include <hip/hip_runtime.h>
#include <hip/hip_bf16.h>

// loss = N * sum(x*x) - sum_d (colsum_d)^2, x is (256, D=100000) fp32 row-major.
// R5: occupancy experiment — 512 blocks x 1024 threads = 2 blocks/CU = 32
// waves/CU (2x the in-flight memory requests of R3). Thread = (rowgroup g
// 0..15 of 16 rows, col-lane c 0..63). Block b owns float4-columns
// [D4*b/512, D4*(b+1)/512) = 48..49 cols. LDS reduce -> one atomicAdd/block.

#define N_ROWS 256
#define NBLK 512
#define CLANES 64
#define RG 16
#define RPG 16

typedef float f32x4 __attribute__((ext_vector_type(4)));

__global__ __launch_bounds__(1024) void tpc_loss_kernel(
    const float* __restrict__ x, float* __restrict__ out, int D4, int D) {
  const int c = threadIdx.x & (CLANES - 1);  // 0..63
  const int g = threadIdx.x >> 6;            // 0..15
  const int c0 = (int)(((long)D4 * blockIdx.x) >> 9);
  const int c1 = (int)(((long)D4 * (blockIdx.x + 1)) >> 9);
  const int ncols = c1 - c0;                 // 48 or 49

  f32x4 s = {0.f, 0.f, 0.f, 0.f};
  float q = 0.f;

  if (c < ncols) {
    const float* p = x + (size_t)g * RPG * D + (size_t)(c0 + c) * 4;
#pragma unroll 16
    for (int r = 0; r < RPG; ++r) {
      f32x4 v = *reinterpret_cast<const f32x4*>(p + (size_t)r * D);
      s += v;
      q += v.x * v.x + v.y * v.y + v.z * v.z + v.w * v.w;
    }
  }

  // Per-wave reduce of q (16 waves).
#pragma unroll
  for (int off = 32; off > 0; off >>= 1) q += __shfl_down(q, off, 64);

  __shared__ f32x4 sh_s[RG][CLANES];  // 16 KB
  __shared__ float sh_q[16];
  sh_s[g][c] = s;                     // inactive cols write zeros
  if ((threadIdx.x & 63) == 0) sh_q[threadIdx.x >> 6] = q;
  __syncthreads();

  // Single-wave epilogue: lane l owns column l.
  if (threadIdx.x < 64) {
    const int l = threadIdx.x;
    f32x4 t = sh_s[0][l];
#pragma unroll
    for (int i = 1; i < RG; ++i) t += sh_s[i][l];
    float ssq = t.x * t.x + t.y * t.y + t.z * t.z + t.w * t.w;
    float qw = (l < 16) ? sh_q[l] : 0.f;
#pragma unroll
    for (int off = 32; off > 0; off >>= 1) {
      ssq += __shfl_down(ssq, off, 64);
      qw  += __shfl_down(qw, off, 64);
    }
    if (l == 0) atomicAdd(out, (float)N_ROWS * qw - ssq);
  }
}

extern "C" void kernel_launch(void* const* d_in, const int* in_sizes, int n_in,
                              void* d_out, int out_size, void* d_ws, size_t ws_size,
                              hipStream_t stream) {
  const float* x = (const float*)d_in[0];
  float* out = (float*)d_out;
  const int total = in_sizes[0];
  const int D = total / N_ROWS;   // 100000
  const int D4 = D / 4;           // 25000

  hipMemsetAsync(d_out, 0, sizeof(float) * out_size, stream);
  tpc_loss_kernel<<<NBLK, 1024, 0, stream>>>(x, out, D4, D);
}

// Round 6
// 25.045 us; speedup vs baseline: 2.4987x; 1.1571x over previous
//
#include <hip/hip_runtime.h>
#include <hip/hip_bf16.h>

// loss = N * sum(x*x) - sum_d (colsum_d)^2, x is (256, D=100000) fp32 row-major.
// R6: single-dispatch graph. R3 load geometry (256 blocks x 1024 threads,
// block b owns float4-cols [D4*b/256, D4*(b+1)/256)). Each block stores its
// partial + a 64-bit MAGIC flag into d_ws (device scope, release). Block 0
// wave 0 spin-polls all 256 flags (acquire), reduces, writes d_out, then
// clears flags so the next graph replay starts clean. No memset node, no
// atomics, no cooperative launch.

#define N_ROWS 256
#define NBLK 256
#define CLANES 128
#define RG 8
#define RPG 32

typedef float f32x4 __attribute__((ext_vector_type(4)));

#define MAGIC 0x5EEDBEEFCAFEF00DULL

__device__ __forceinline__ float tpc_block_partial(
    const float* __restrict__ x, int D4, int D) {
  const int c = threadIdx.x & (CLANES - 1);  // 0..127
  const int g = threadIdx.x >> 7;            // 0..7
  const int c0 = (int)(((long)D4 * blockIdx.x) >> 8);
  const int c1 = (int)(((long)D4 * (blockIdx.x + 1)) >> 8);
  const int ncols = c1 - c0;                 // 97 or 98

  f32x4 s = {0.f, 0.f, 0.f, 0.f};
  float q = 0.f;

  if (c < ncols) {
    const float* p = x + (size_t)g * RPG * D + (size_t)(c0 + c) * 4;
#pragma unroll 16
    for (int r = 0; r < RPG; ++r) {
      f32x4 v = *reinterpret_cast<const f32x4*>(p + (size_t)r * D);
      s += v;
      q += v.x * v.x + v.y * v.y + v.z * v.z + v.w * v.w;
    }
  }

#pragma unroll
  for (int off = 32; off > 0; off >>= 1) q += __shfl_down(q, off, 64);

  __shared__ f32x4 sh_s[RG][CLANES];  // 16 KB
  __shared__ float sh_q[16];
  sh_s[g][c] = s;  // inactive cols wrote zeros
  if ((threadIdx.x & 63) == 0) sh_q[threadIdx.x >> 6] = q;
  __syncthreads();

  float result = 0.f;
  if (threadIdx.x < 64) {
    const int l = threadIdx.x;
    float ssq = 0.f;
#pragma unroll
    for (int half = 0; half < 2; ++half) {
      const int cc = l + half * 64;
      f32x4 t = sh_s[0][cc];
#pragma unroll
      for (int i = 1; i < RG; ++i) t += sh_s[i][cc];
      ssq += t.x * t.x + t.y * t.y + t.z * t.z + t.w * t.w;
    }
    float qw = (l < 16) ? sh_q[l] : 0.f;
#pragma unroll
    for (int off = 32; off > 0; off >>= 1) {
      ssq += __shfl_down(ssq, off, 64);
      qw  += __shfl_down(qw, off, 64);
    }
    result = (float)N_ROWS * qw - ssq;  // valid on thread 0
  }
  return result;
}

__global__ __launch_bounds__(1024) void tpc_onepass_kernel(
    const float* __restrict__ x, float* __restrict__ ws_f,
    unsigned long long* __restrict__ ws_flag, float* __restrict__ out,
    int D4, int D) {
  float part = tpc_block_partial(x, D4, D);
  if (threadIdx.x == 0) {
    __hip_atomic_store(&ws_f[blockIdx.x], part, __ATOMIC_RELAXED,
                       __HIP_MEMORY_SCOPE_AGENT);
    __hip_atomic_store(&ws_flag[blockIdx.x], MAGIC, __ATOMIC_RELEASE,
                       __HIP_MEMORY_SCOPE_AGENT);
  }

  // Block 0, wave 0: wait for all partials, reduce, write out, clear flags.
  if (blockIdx.x == 0 && threadIdx.x < 64) {
    const int l = threadIdx.x;
#pragma unroll
    for (int i = 0; i < 4; ++i) {
      while (__hip_atomic_load(&ws_flag[l + 64 * i], __ATOMIC_ACQUIRE,
                               __HIP_MEMORY_SCOPE_AGENT) != MAGIC) {
        __builtin_amdgcn_s_sleep(1);
      }
    }
    float v = 0.f;
#pragma unroll
    for (int i = 0; i < 4; ++i)
      v += __hip_atomic_load(&ws_f[l + 64 * i], __ATOMIC_RELAXED,
                             __HIP_MEMORY_SCOPE_AGENT);
#pragma unroll
    for (int off = 32; off > 0; off >>= 1) v += __shfl_down(v, off, 64);
    if (l == 0) out[0] = v;
    // Clear consumed flags so the next replay starts clean.
#pragma unroll
    for (int i = 0; i < 4; ++i)
      __hip_atomic_store(&ws_flag[l + 64 * i], 0ULL, __ATOMIC_RELAXED,
                         __HIP_MEMORY_SCOPE_AGENT);
  }
}

// Fallback if ws is too small: R3 path (memset + per-block atomicAdd).
__global__ __launch_bounds__(1024) void tpc_atomic_kernel(
    const float* __restrict__ x, float* __restrict__ out, int D4, int D) {
  float part = tpc_block_partial(x, D4, D);
  if (threadIdx.x == 0) atomicAdd(out, part);
}

extern "C" void kernel_launch(void* const* d_in, const int* in_sizes, int n_in,
                              void* d_out, int out_size, void* d_ws, size_t ws_size,
                              hipStream_t stream) {
  const float* x = (const float*)d_in[0];
  float* out = (float*)d_out;
  const int total = in_sizes[0];
  const int D = total / N_ROWS;   // 100000
  const int D4 = D / 4;           // 25000

  if (ws_size >= 4096) {
    float* ws_f = (float*)d_ws;                                   // 1 KB
    unsigned long long* ws_flag =
        (unsigned long long*)((char*)d_ws + 1024);                // 2 KB
    tpc_onepass_kernel<<<NBLK, 1024, 0, stream>>>(x, ws_f, ws_flag, out, D4, D);
  } else {
    hipMemsetAsync(d_out, 0, sizeof(float) * out_size, stream);
    tpc_atomic_kernel<<<NBLK, 1024, 0, stream>>>(x, out, D4, D);
  }
}

// Round 7
// 24.885 us; speedup vs baseline: 2.5148x; 1.0064x over previous
//
#include <hip/hip_runtime.h>
#include <hip/hip_bf16.h>

// loss = N * sum(x*x) - sum_d (colsum_d)^2, x is (256, D=100000) fp32 row-major.
// R7: R6 single-dispatch structure + 64B-ALIGNED column windows.
// D4 = 25000 float4-cols = 6250 units of 4 float4 (64B). Block b owns units
// [6250*b/256, 6250*(b+1)/256) -> 24..25 units = 96..100 float4-cols. Every
// 64-lane wave load now starts 64B-aligned -> exactly 16 cache lines per 1KB
// access (was 17 when c0 was only 16B-aligned). Flag/partial protocol as R6.

#define N_ROWS 256
#define NBLK 256
#define CLANES 128
#define RG 8
#define RPG 32
#define UNITS 6250  // D4 / 4

typedef float f32x4 __attribute__((ext_vector_type(4)));

#define MAGIC 0x5EEDBEEFCAFEF00DULL

__device__ __forceinline__ float tpc_block_partial(
    const float* __restrict__ x, int D4, int D) {
  const int c = threadIdx.x & (CLANES - 1);  // 0..127
  const int g = threadIdx.x >> 7;            // 0..7
  const int u0 = (int)(((long)UNITS * blockIdx.x) >> 8);
  const int u1 = (int)(((long)UNITS * (blockIdx.x + 1)) >> 8);
  const int c0 = u0 * 4;
  const int ncols = (u1 - u0) * 4;           // 96 or 100

  f32x4 s = {0.f, 0.f, 0.f, 0.f};
  float q = 0.f;

  if (c < ncols) {
    const float* p = x + (size_t)g * RPG * D + (size_t)(c0 + c) * 4;
#pragma unroll 16
    for (int r = 0; r < RPG; ++r) {
      f32x4 v = *reinterpret_cast<const f32x4*>(p + (size_t)r * D);
      s += v;
      q += v.x * v.x + v.y * v.y + v.z * v.z + v.w * v.w;
    }
  }

#pragma unroll
  for (int off = 32; off > 0; off >>= 1) q += __shfl_down(q, off, 64);

  __shared__ f32x4 sh_s[RG][CLANES];  // 16 KB
  __shared__ float sh_q[16];
  sh_s[g][c] = s;  // inactive cols wrote zeros
  if ((threadIdx.x & 63) == 0) sh_q[threadIdx.x >> 6] = q;
  __syncthreads();

  float result = 0.f;
  if (threadIdx.x < 64) {
    const int l = threadIdx.x;
    float ssq = 0.f;
#pragma unroll
    for (int half = 0; half < 2; ++half) {
      const int cc = l + half * 64;
      f32x4 t = sh_s[0][cc];
#pragma unroll
      for (int i = 1; i < RG; ++i) t += sh_s[i][cc];
      ssq += t.x * t.x + t.y * t.y + t.z * t.z + t.w * t.w;
    }
    float qw = (l < 16) ? sh_q[l] : 0.f;
#pragma unroll
    for (int off = 32; off > 0; off >>= 1) {
      ssq += __shfl_down(ssq, off, 64);
      qw  += __shfl_down(qw, off, 64);
    }
    result = (float)N_ROWS * qw - ssq;  // valid on thread 0
  }
  return result;
}

__global__ __launch_bounds__(1024) void tpc_onepass_kernel(
    const float* __restrict__ x, float* __restrict__ ws_f,
    unsigned long long* __restrict__ ws_flag, float* __restrict__ out,
    int D4, int D) {
  float part = tpc_block_partial(x, D4, D);
  if (threadIdx.x == 0) {
    __hip_atomic_store(&ws_f[blockIdx.x], part, __ATOMIC_RELAXED,
                       __HIP_MEMORY_SCOPE_AGENT);
    __hip_atomic_store(&ws_flag[blockIdx.x], MAGIC, __ATOMIC_RELEASE,
                       __HIP_MEMORY_SCOPE_AGENT);
  }

  // Block 0, wave 0: wait for all partials, reduce, write out, clear flags.
  if (blockIdx.x == 0 && threadIdx.x < 64) {
    const int l = threadIdx.x;
#pragma unroll
    for (int i = 0; i < 4; ++i) {
      while (__hip_atomic_load(&ws_flag[l + 64 * i], __ATOMIC_ACQUIRE,
                               __HIP_MEMORY_SCOPE_AGENT) != MAGIC) {
        __builtin_amdgcn_s_sleep(1);
      }
    }
    float v = 0.f;
#pragma unroll
    for (int i = 0; i < 4; ++i)
      v += __hip_atomic_load(&ws_f[l + 64 * i], __ATOMIC_RELAXED,
                             __HIP_MEMORY_SCOPE_AGENT);
#pragma unroll
    for (int off = 32; off > 0; off >>= 1) v += __shfl_down(v, off, 64);
    if (l == 0) out[0] = v;
    // Clear consumed flags so the next replay starts clean.
#pragma unroll
    for (int i = 0; i < 4; ++i)
      __hip_atomic_store(&ws_flag[l + 64 * i], 0ULL, __ATOMIC_RELAXED,
                         __HIP_MEMORY_SCOPE_AGENT);
  }
}

// Fallback if ws is too small: memset + per-block atomicAdd.
__global__ __launch_bounds__(1024) void tpc_atomic_kernel(
    const float* __restrict__ x, float* __restrict__ out, int D4, int D) {
  float part = tpc_block_partial(x, D4, D);
  if (threadIdx.x == 0) atomicAdd(out, part);
}

extern "C" void kernel_launch(void* const* d_in, const int* in_sizes, int n_in,
                              void* d_out, int out_size, void* d_ws, size_t ws_size,
                              hipStream_t stream) {
  const float* x = (const float*)d_in[0];
  float* out = (float*)d_out;
  const int total = in_sizes[0];
  const int D = total / N_ROWS;   // 100000
  const int D4 = D / 4;           // 25000

  if (ws_size >= 4096) {
    float* ws_f = (float*)d_ws;                                   // 1 KB
    unsigned long long* ws_flag =
        (unsigned long long*)((char*)d_ws + 1024);                // 2 KB
    tpc_onepass_kernel<<<NBLK, 1024, 0, stream>>>(x, ws_f, ws_flag, out, D4, D);
  } else {
    hipMemsetAsync(d_out, 0, sizeof(float) * out_size, stream);
    tpc_atomic_kernel<<<NBLK, 1024, 0, stream>>>(x, out, D4, D);
  }
}